// Round 11
// baseline (1723.041 us; speedup 1.0000x reference)
//
#include <hip/hip_runtime.h>

// Problem constants
#define NPTS 8192
#define NB   32
#define NG   256
#define NK   32
#define ND   384
#define NH   6
#define NLK  64
#define NF   1536
#define NHD  64
#define NL   12
#define MM   2048   // NB*NLK token rows

typedef unsigned short u16;
typedef unsigned long long u64;
typedef __attribute__((ext_vector_type(8))) short short8;    // bf16x8 MFMA frag
typedef __attribute__((ext_vector_type(16))) float f32x16;   // 32x32 MFMA acc
typedef __attribute__((ext_vector_type(4))) unsigned short ushort4v;

// per-layer transposed-weight plane layout (element offsets within one plane)
#define PL_PRE   147456ull          // pe_w3 (98304) + pos_w2 (49152)
#define PL_LAYER 1769472ull         // qkv|wo|wi|wo2 for one layer
#define WT_ELEMS (PL_PRE + 12ull*PL_LAYER)   // 21381120 u16 per plane

__device__ __forceinline__ float bf2f(u16 v){
  unsigned int u = ((unsigned int)v) << 16;
  float f; __builtin_memcpy(&f, &u, 4); return f;
}
__device__ __forceinline__ float ldf(const void* p, size_t i, bool bf){
  if(bf) return bf2f(((const u16*)p)[i]);
  return ((const float*)p)[i];
}
__device__ __forceinline__ u16 f2bf(float f){
  unsigned int x; __builtin_memcpy(&x, &f, 4);
  x += 0x7fffu + ((x >> 16) & 1u);
  return (u16)(x >> 16);
}
// split f32 -> (hi, lo) bf16 planes; hi RNE, lo = RNE(residual)
__device__ __forceinline__ void split2(float v, u16& hi, u16& lo){
  hi = f2bf(v);
  lo = f2bf(v - bf2f(hi));
}

// ---------------------------------------------------------------- normalize (+ inline dtype detect)
__device__ __forceinline__ float blockMax256(float v, float* sb, int tid){
  for(int off=32; off; off>>=1) v = fmaxf(v, __shfl_down(v, off));
  __syncthreads();
  if((tid&63)==0) sb[tid>>6] = v;
  __syncthreads();
  return fmaxf(fmaxf(sb[0],sb[1]), fmaxf(sb[2],sb[3]));
}

__global__ __launch_bounds__(256) void k_normalize(const void* __restrict__ pts,
                                                   float* __restrict__ xn,
                                                   int* __restrict__ flag){
#pragma clang fp contract(off)
  int b = blockIdx.x, tid = threadIdx.x;
  __shared__ float sb[4];
  __shared__ int sbad;
  if(tid==0) sbad = 0;
  __syncthreads();
  {
    const u16* p16 = (const u16*)pts;
    int hit=0;
    for(int i=tid; i<4096; i+=256){
      unsigned e = (p16[i] >> 7) & 0xFFu;
      if(e >= 0x90u) hit=1;
    }
    if(hit) atomicOr(&sbad, 1);
  }
  __syncthreads();
  const bool bf = (sbad == 0);     // 1 = bf16, 0 = f32
  if(b==0 && tid==0) flag[0] = bf ? 1 : 0;
  const size_t base = (size_t)b*NPTS*3;
  float mn0=1e30f,mn1=1e30f,mn2=1e30f, mx0=-1e30f,mx1=-1e30f,mx2=-1e30f;
  for(int n=tid; n<NPTS; n+=256){
    float x0=ldf(pts,base+n*3,bf), x1=ldf(pts,base+n*3+1,bf), x2=ldf(pts,base+n*3+2,bf);
    mn0=fminf(mn0,x0); mx0=fmaxf(mx0,x0);
    mn1=fminf(mn1,x1); mx1=fmaxf(mx1,x1);
    mn2=fminf(mn2,x2); mx2=fmaxf(mx2,x2);
  }
  mx0=blockMax256(mx0,sb,tid); mn0=-blockMax256(-mn0,sb,tid);
  mx1=blockMax256(mx1,sb,tid); mn1=-blockMax256(-mn1,sb,tid);
  mx2=blockMax256(mx2,sb,tid); mn2=-blockMax256(-mn2,sb,tid);
  float c0=0.5f*(mn0+mx0), c1=0.5f*(mn1+mx1), c2=0.5f*(mn2+mx2);
  float mr=0.0f;
  for(int n=tid; n<NPTS; n+=256){
    float d0=ldf(pts,base+n*3,bf)-c0, d1=ldf(pts,base+n*3+1,bf)-c1, d2=ldf(pts,base+n*3+2,bf)-c2;
    float nr = sqrtf((d0*d0 + d1*d1) + d2*d2);
    mr = fmaxf(mr, nr);
  }
  float radius = blockMax256(mr, sb, tid);
  float* XO = xn + base;
  for(int n=tid; n<NPTS; n+=256){
    XO[n*3  ] = (ldf(pts,base+n*3  ,bf)-c0)/radius;
    XO[n*3+1] = (ldf(pts,base+n*3+1,bf)-c1)/radius;
    XO[n*3+2] = (ldf(pts,base+n*3+2,bf)-c2)/radius;
  }
}

// ---------------------------------------------------------------- fused FPS + keep + weight transposes
// R11: 1024 threads. FPS path: 8 pts/thread (halves the serial select chain,
// doubles waves/SIMD for latency hiding). Selection is bit-identical: candidate
// set unchanged; per-thread strict-> picks min n among ties (n=s*1024+tid
// increasing in s); global key (dist, NPTS-1-n) still max-dist/min-n.
__device__ __forceinline__ void kmax_dpp_step(unsigned& hi, unsigned& lo, unsigned oh, unsigned ol){
  bool g = (oh > hi) || (oh == hi && ol > lo);
  hi = g ? oh : hi; lo = g ? ol : lo;
}
#define KMAX_DPP(CTRL) { \
  unsigned oh=(unsigned)__builtin_amdgcn_update_dpp(0,(int)kh,(CTRL),0xf,0xf,true); \
  unsigned ol=(unsigned)__builtin_amdgcn_update_dpp(0,(int)kl,(CTRL),0xf,0xf,true); \
  kmax_dpp_step(kh,kl,oh,ol); }

__global__ __launch_bounds__(1024) void k_fps_trans(
    const float* __restrict__ xn, float* __restrict__ centers,
    const void* __restrict__ noise, int* __restrict__ keep,
    const void* __restrict__ pe_w3, const void* __restrict__ pos_w2,
    const void* __restrict__ wqkv, const void* __restrict__ wo,
    const void* __restrict__ wi,   const void* __restrict__ wo2,
    u16* __restrict__ wthi, u16* __restrict__ wtlo,
    const int* __restrict__ flag)
{
  __shared__ float xs[NPTS*3];   // 96 KB coord mirror (fps) / transpose tile / noise buf
  __shared__ u64 skey[3];
  __shared__ int sc[NG];
  int tid = threadIdx.x;

  if(blockIdx.x >= 64){
    // ---------------- transpose path (1024 threads, one elem each) ----------------
    const bool bf = flag[0]!=0;
    float (*t)[33] = reinterpret_cast<float(*)[33]>(xs);
    int gid = blockIdx.x - 64;
    const void* W; int Kd, Nd; size_t woff, doff; int local;
    if(gid < 96){        W=pe_w3;  Kd=256; Nd=384; woff=0; doff=0;      local=gid; }
    else if(gid < 144){  W=pos_w2; Kd=128; Nd=384; woff=0; doff=98304;  local=gid-96; }
    else{
      int g2 = gid - 144; int l = g2 / 1728; int id = g2 % 1728;
      size_t lb = PL_PRE + (size_t)l*PL_LAYER;
      if(id < 432){        W=wqkv; Kd=384;  Nd=1152; woff=(size_t)l*442368; doff=lb;          local=id; }
      else if(id < 576){   W=wo;   Kd=384;  Nd=384;  woff=(size_t)l*147456; doff=lb+442368;   local=id-432; }
      else if(id < 1152){  W=wi;   Kd=384;  Nd=1536; woff=(size_t)l*589824; doff=lb+589824;   local=id-576; }
      else {               W=wo2;  Kd=1536; Nd=384;  woff=(size_t)l*589824; doff=lb+1179648;  local=id-1152; }
    }
    int ntiles = Nd >> 5;
    int n0 = (local % ntiles)*32, k0 = (local / ntiles)*32;
    {
      int kr = tid>>5, nc = tid&31;
      t[kr][nc] = ldf(W, woff + (size_t)(k0+kr)*Nd + n0+nc, bf);
    }
    __syncthreads();
    {
      int nr = tid>>5, kc = tid&31;
      float v = t[kc][nr];
      u16 hi,lo; split2(v,hi,lo);
      size_t o = doff + (size_t)(n0+nr)*Kd + k0+kc;
      wthi[o]=hi; wtlo[o]=lo;
    }
    return;
  }

  if(blockIdx.x >= 32){
    // ---------------- keep path (rank of noise per batch) ----------------
    const bool bf = flag[0]!=0;
    int b = blockIdx.x - 32;
    float* nv = xs;
    if(tid < NG) nv[tid] = ldf(noise, (size_t)b*NG+tid, bf);
    __syncthreads();
    if(tid < NG){
      float v = nv[tid]; int r = 0;
      for(int j=0; j<NG; j++){
        float u = nv[j];
        r += (u < v) || (u == v && j < tid);
      }
      if(r < NLK) keep[b*NLK + r] = tid;
    }
    return;
  }

  // ---------------- FPS path (8 pts/thread; math identical per point) ----------------
  {
#pragma clang fp contract(off)
    int b = blockIdx.x;
    int lane = tid & 63;
    const float* X = xn + (size_t)b*NPTS*3;
    float px[8],py[8],pz[8],dd[8];
#pragma unroll
    for(int s=0;s<8;s++){
      int n = s*1024 + tid;
      px[s]=X[n*3]; py[s]=X[n*3+1]; pz[s]=X[n*3+2];
      dd[s]=1e10f;
    }
    for(int i=tid; i<NPTS*3; i+=1024) xs[i] = X[i];
    if(tid==0){ skey[0]=0ull; skey[1]=0ull; skey[2]=0ull; sc[0]=0; }
    __syncthreads();
    float lx = xs[0], ly = xs[1], lz = xs[2];
    for(int i=1;i<NG;i++){
      int c = i % 3;
      float bv=-1.0f; int bs=0;
#pragma unroll
      for(int s=0;s<8;s++){
        float dx=px[s]-lx, dy=py[s]-ly, dz=pz[s]-lz;
        float d=(dx*dx + dy*dy) + dz*dz;
        d = fminf(dd[s], d); dd[s]=d;
        if(d > bv){ bv=d; bs=s; }   // strict >: first (smallest n) on ties
      }
      int bn = bs*1024 + tid;
      unsigned kh; __builtin_memcpy(&kh,&bv,4);
      unsigned kl = (unsigned)(NPTS-1-bn);
      KMAX_DPP(0x111)
      KMAX_DPP(0x112)
      KMAX_DPP(0x114)
      KMAX_DPP(0x118)
      KMAX_DPP(0x142)
      KMAX_DPP(0x143)
      if(lane==63) atomicMax(&skey[c], ((u64)kh<<32) | (u64)kl);
      __syncthreads();
      u64 k64 = skey[c];
      int n = (NPTS-1) - (int)(k64 & 0xFFFFFFFFull);
      n &= (NPTS-1);
      if(tid==0){ sc[i]=n; skey[(i+2)%3]=0ull; }
      lx = xs[n*3]; ly = xs[n*3+1]; lz = xs[n*3+2];
    }
    __syncthreads();
    if(tid < NG){
      int n = sc[tid] & (NPTS-1);
      centers[((size_t)b*NG+tid)*3  ] = xs[n*3];
      centers[((size_t)b*NG+tid)*3+1] = xs[n*3+1];
      centers[((size_t)b*NG+tid)*3+2] = xs[n*3+2];
    }
  }
}

// ---------------------------------------------------------------- fused kNN + embed (same grid/block mapping)
__global__ __launch_bounds__(256) void k_knn_embed(
    const float* __restrict__ xn, const float* __restrict__ centers,
    const int* __restrict__ keep,
    const void* __restrict__ w1, const void* __restrict__ b1,
    const void* __restrict__ w2, const void* __restrict__ b2,
    const void* __restrict__ pw1, const void* __restrict__ pb1,
    u16* __restrict__ mfhi, u16* __restrict__ mflo,
    u16* __restrict__ phhi, u16* __restrict__ phlo,
    const int* __restrict__ flag)
{
  int blk=blockIdx.x; int b=blk>>6; int j=blk&63; int tid=threadIdx.x;
  const bool bf = flag[0] != 0;
  __shared__ __align__(16) float sd[NPTS];   // 32KB; reused as f1t (128*36 floats) in embed
  __shared__ int   sel[NK];
  __shared__ float rv[4]; __shared__ int rn[4];
  __shared__ int   sseln;
  __shared__ float pat[NK*3];
  int g = keep[b*NLK + j] & (NG-1);
  const float* C = centers + ((size_t)b*NG + g)*3;
  float c0=C[0], c1=C[1], c2=C[2];
  const float* X = xn + (size_t)b*NPTS*3;
  {
#pragma clang fp contract(off)
    float cc = (c0*c0 + c1*c1) + c2*c2;
    for(int n=tid; n<NPTS; n+=256){
      float x0=X[n*3], x1=X[n*3+1], x2=X[n*3+2];
      float xx=(x0*x0 + x1*x1) + x2*x2;
      float dt=(c0*x0 + c1*x1) + c2*x2;
      sd[n] = (cc + xx) - 2.0f*dt;
    }
  }
  __syncthreads();
  float dl[32];
  for(int s=0;s<32;s++) dl[s] = sd[s*256 + tid];
  unsigned int alive = 0xffffffffu;
  for(int r=0; r<NK; r++){
    float bv=1e30f; int bn=0x7fffffff;
    for(int s=0;s<32;s++){
      if(alive & (1u<<s)){
        float v = dl[s];
        if(v < bv){ bv=v; bn=s*256+tid; }
      }
    }
    for(int off=32;off;off>>=1){
      float ov=__shfl_down(bv,off); int on=__shfl_down(bn,off);
      if(ov<bv || (ov==bv && on<bn)){ bv=ov; bn=on; }
    }
    if((tid&63)==0){ rv[tid>>6]=bv; rn[tid>>6]=bn; }
    __syncthreads();
    if(tid==0){
      float v=rv[0]; int n=rn[0];
      for(int w=1;w<4;w++) if(rv[w]<v || (rv[w]==v && rn[w]<n)){ v=rv[w]; n=rn[w]; }
      n &= (NPTS-1);
      sseln=n; sel[r]=n;
    }
    __syncthreads();
    int n = sseln;
    if((n & 255) == tid) alive &= ~(1u << (n >> 8));
  }
  __syncthreads();
  if(tid < NK){
    int n = sel[tid] & (NPTS-1);
    pat[tid*3+0] = X[n*3  ]-c0;
    pat[tid*3+1] = X[n*3+1]-c1;
    pat[tid*3+2] = X[n*3+2]-c2;
  }
  __syncthreads();
  // ---------------- embed part (sd reused as f1t) ----------------
  float* f1t = sd;                 // [jj][k], pitch 36; 4608 floats < 8192
  int row = b*NLK + j;
  for(int i=0;i<16;i++){
    int idx = tid + i*256;
    int k = idx>>7, m = idx&127;
    float v = ldf(b1,m,bf)
            + pat[k*3+0]*ldf(w1,        m,bf)
            + pat[k*3+1]*ldf(w1, 128 + m,bf)
            + pat[k*3+2]*ldf(w1, 256 + m,bf);
    f1t[m*36 + k] = fmaxf(v, 0.0f);
  }
  __syncthreads();
  float acc[NK];
  {
    float bv = ldf(b2, tid, bf);
#pragma unroll
    for(int k=0;k<NK;k++) acc[k]=bv;
  }
  for(int jj=0;jj<128;jj++){
    float wv = ldf(w2, (size_t)jj*256+tid, bf);
    const float* fr = &f1t[jj*36];
#pragma unroll
    for(int k8=0;k8<8;k8++){
      float4 fv = *reinterpret_cast<const float4*>(fr + k8*4);
      acc[k8*4+0] = fmaf(fv.x, wv, acc[k8*4+0]);
      acc[k8*4+1] = fmaf(fv.y, wv, acc[k8*4+1]);
      acc[k8*4+2] = fmaf(fv.z, wv, acc[k8*4+2]);
      acc[k8*4+3] = fmaf(fv.w, wv, acc[k8*4+3]);
    }
  }
  float mx = acc[0];
#pragma unroll
  for(int k=1;k<NK;k++) mx = fmaxf(mx, acc[k]);
  { u16 hi,lo; split2(mx,hi,lo);
    mfhi[(size_t)row*256 + tid]=hi; mflo[(size_t)row*256 + tid]=lo; }
  if(tid < 128){
    float v = ldf(pb1,tid,bf)
            + c0*ldf(pw1,        tid,bf)
            + c1*ldf(pw1, 128 + tid,bf)
            + c2*ldf(pw1, 256 + tid,bf);
    v = fmaxf(v, 0.0f);
    u16 hi,lo; split2(v,hi,lo);
    phhi[(size_t)row*128 + tid]=hi; phlo[(size_t)row*128 + tid]=lo;
  }
}

// ---------------------------------------------------------------- batched per-layer transpose (fallback path only)
__global__ __launch_bounds__(256) void k_transpose4(
    const void* __restrict__ wqkv, const void* __restrict__ wo,
    const void* __restrict__ wi,   const void* __restrict__ wo2,
    int l, u16* __restrict__ dhi, u16* __restrict__ dlo,
    const int* __restrict__ flag){
  __shared__ float t[32][33];
  const bool bf = flag[0]!=0;
  int id = blockIdx.x;
  const void* W; int Kd, Nd; size_t woff, doff; int local;
  if(id < 432){        W=wqkv; Kd=384;  Nd=1152; woff=(size_t)l*442368; doff=PL_PRE;          local=id; }
  else if(id < 576){   W=wo;   Kd=384;  Nd=384;  woff=(size_t)l*147456; doff=PL_PRE+442368;   local=id-432; }
  else if(id < 1152){  W=wi;   Kd=384;  Nd=1536; woff=(size_t)l*589824; doff=PL_PRE+589824;   local=id-576; }
  else {               W=wo2;  Kd=1536; Nd=384;  woff=(size_t)l*589824; doff=PL_PRE+1179648;  local=id-1152; }
  int ntiles = Nd >> 5;
  int n0 = (local % ntiles)*32, k0 = (local / ntiles)*32;
  for(int i=0;i<4;i++){
    int idx = threadIdx.x + i*256; int kr = idx>>5, nc = idx&31;
    t[kr][nc] = ldf(W, woff + (size_t)(k0+kr)*Nd + n0+nc, bf);
  }
  __syncthreads();
  for(int i=0;i<4;i++){
    int idx = threadIdx.x + i*256; int nr = idx>>5, kc = idx&31;
    float v = t[kc][nr];
    u16 hi,lo; split2(v,hi,lo);
    size_t o = doff + (size_t)(n0+nr)*Kd + k0+kc;
    dhi[o]=hi; dlo[o]=lo;
  }
}

// ---------------------------------------------------------------- LayerNorm -> bf16 hi/lo planes
__global__ __launch_bounds__(128) void k_ln_split(const float* __restrict__ X,
                                                  const void* __restrict__ gb, size_t go,
                                                  u16* __restrict__ Yhi, u16* __restrict__ Ylo,
                                                  const int* __restrict__ flag){
  int row=blockIdx.x, tid=threadIdx.x;
  const bool bf = flag[0] != 0;
  const float* x = X + (size_t)row*ND;
  __shared__ float sbuf[2];
  float v0=x[tid], v1=x[tid+128], v2=x[tid+256];
  float s = v0+v1+v2;
  for(int off=32;off;off>>=1) s += __shfl_down(s,off);
  if((tid&63)==0) sbuf[tid>>6]=s;
  __syncthreads();
  float mean = (sbuf[0]+sbuf[1]) * (1.0f/(float)ND);
  __syncthreads();
  float d0=v0-mean, d1=v1-mean, d2=v2-mean;
  s = d0*d0 + d1*d1 + d2*d2;
  for(int off=32;off;off>>=1) s += __shfl_down(s,off);
  if((tid&63)==0) sbuf[tid>>6]=s;
  __syncthreads();
  float var = (sbuf[0]+sbuf[1]) * (1.0f/(float)ND);
  float rstd = 1.0f / sqrtf(var + 1e-5f);
  float o0 = d0*rstd*ldf(gb,go+tid    ,bf) + ldf(gb,go+ND+tid    ,bf);
  float o1 = d1*rstd*ldf(gb,go+tid+128,bf) + ldf(gb,go+ND+tid+128,bf);
  float o2 = d2*rstd*ldf(gb,go+tid+256,bf) + ldf(gb,go+ND+tid+256,bf);
  u16 hi,lo; size_t rb = (size_t)row*ND;
  split2(o0,hi,lo); Yhi[rb+tid    ]=hi; Ylo[rb+tid    ]=lo;
  split2(o1,hi,lo); Yhi[rb+tid+128]=hi; Ylo[rb+tid+128]=lo;
  split2(o2,hi,lo); Yhi[rb+tid+256]=hi; Ylo[rb+tid+256]=lo;
}

// ---------------------------------------------------------------- MFMA GEMM, bf16x3 split precision, 32x32x16
// R9 proven config: TM=64 only (TM=128 was neutral/negative in R10).
// Reg-staged, 2-deep named prefetch, one barrier/K-step.
template<int TM, int ACT, bool RES, bool OSPLIT>
__global__ __launch_bounds__(256) void k_gemm_mfma(
    const u16* __restrict__ Ahi, const u16* __restrict__ Alo,
    const u16* __restrict__ Whi, const u16* __restrict__ Wlo, size_t wo,
    const void* __restrict__ bias, size_t bo, const int* __restrict__ flag,
    const float* __restrict__ res, float* __restrict__ Cf,
    u16* __restrict__ Ohi, u16* __restrict__ Olo,
    int N, int K)
{
  constexpr int TN = 64;
  __shared__ __align__(16) u16 sAh[2][TM*40];
  __shared__ __align__(16) u16 sAl[2][TM*40];
  __shared__ __align__(16) u16 sBh[2][TN*40];
  __shared__ __align__(16) u16 sBl[2][TN*40];
  int tid = threadIdx.x;
  int wave = tid >> 6, lane = tid & 63;
  int wm = wave >> 1, wn = wave & 1;
  int l31 = lane & 31, half = lane >> 5;
  int row0 = blockIdx.y*TM, col0 = blockIdx.x*TN;
  const bool bf = flag[0] != 0;
  f32x16 acc;
#pragma unroll
  for(int r=0;r<16;r++) acc[r]=0.f;

  const int sr  = tid >> 2;
  const int scc = (tid & 3) * 8;
  const u16* gAh = Ahi + (size_t)(row0+sr)*K + scc;
  const u16* gAl = Alo + (size_t)(row0+sr)*K + scc;
  const u16* gBh = Whi + wo + (size_t)(col0+sr)*K + scc;
  const u16* gBl = Wlo + wo + (size_t)(col0+sr)*K + scc;
  const int ldst = sr*40 + scc;

  // two named prefetch sets (set0 = even K-steps, set1 = odd)
  uint4 rah0 = *reinterpret_cast<const uint4*>(gAh);
  uint4 ral0 = *reinterpret_cast<const uint4*>(gAl);
  uint4 rbh0 = *reinterpret_cast<const uint4*>(gBh);
  uint4 rbl0 = *reinterpret_cast<const uint4*>(gBl);
  uint4 rah1 = *reinterpret_cast<const uint4*>(gAh + 32);
  uint4 ral1 = *reinterpret_cast<const uint4*>(gAl + 32);
  uint4 rbh1 = *reinterpret_cast<const uint4*>(gBh + 32);
  uint4 rbl1 = *reinterpret_cast<const uint4*>(gBl + 32);

  const int nk = K >> 5;   // even for all instantiations (K in {128,256,384,1536})

#define GEMM_STEP(S, TT) { \
    *reinterpret_cast<uint4*>(&sAh[S][ldst]) = rah##S; \
    *reinterpret_cast<uint4*>(&sAl[S][ldst]) = ral##S; \
    *reinterpret_cast<uint4*>(&sBh[S][ldst]) = rbh##S; \
    *reinterpret_cast<uint4*>(&sBl[S][ldst]) = rbl##S; \
    __syncthreads(); \
    if((TT)+2 < nk){ \
      const int ko = ((TT)+2) << 5; \
      rah##S = *reinterpret_cast<const uint4*>(gAh + ko); \
      ral##S = *reinterpret_cast<const uint4*>(gAl + ko); \
      rbh##S = *reinterpret_cast<const uint4*>(gBh + ko); \
      rbl##S = *reinterpret_cast<const uint4*>(gBl + ko); \
    } \
    _Pragma("unroll") \
    for(int ks=0; ks<2; ks++){ \
      int aoff = (wm*32 + l31)*40 + ks*16 + half*8; \
      int boff = (wn*32 + l31)*40 + ks*16 + half*8; \
      short8 ah = *reinterpret_cast<const short8*>(&sAh[S][aoff]); \
      short8 al = *reinterpret_cast<const short8*>(&sAl[S][aoff]); \
      short8 bh = *reinterpret_cast<const short8*>(&sBh[S][boff]); \
      short8 bl = *reinterpret_cast<const short8*>(&sBl[S][boff]); \
      acc = __builtin_amdgcn_mfma_f32_32x32x16_bf16(ah, bh, acc, 0,0,0); \
      acc = __builtin_amdgcn_mfma_f32_32x32x16_bf16(ah, bl, acc, 0,0,0); \
      acc = __builtin_amdgcn_mfma_f32_32x32x16_bf16(al, bh, acc, 0,0,0); \
    } \
  }

  for(int t=0; t<nk; t+=2){
    GEMM_STEP(0, t)
    GEMM_STEP(1, t+1)
  }
#undef GEMM_STEP

  int col = col0 + wn*32 + l31;
  float bv = ldf(bias, bo+col, bf);
#pragma unroll
  for(int r=0;r<16;r++){
    int row = row0 + wm*32 + (r&3) + 8*(r>>2) + 4*half;
    float v = acc[r] + bv;
    if(ACT==1){
      float xx = v;
      v = 0.5f*xx*(1.0f + tanhf(0.7978845608028654f*(xx + 0.044715f*xx*xx*xx)));
    }
    if(RES) v += res[(size_t)row*N + col];
    if(OSPLIT){
      u16 hi,lo; split2(v,hi,lo);
      Ohi[(size_t)row*N + col]=hi; Olo[(size_t)row*N + col]=lo;
    }else{
      Cf[(size_t)row*N + col]=v;
    }
  }
}

// ---------------------------------------------------------------- attention (f32 math, register-tiled) -> bf16 planes
// R2/R4 known-good unsplit version: grid NB*NH, 4x4 register tiles per thread.
__global__ __launch_bounds__(256) void k_attn_pl(const float* __restrict__ qkv,
                                                 u16* __restrict__ ohi,
                                                 u16* __restrict__ olo){
  __shared__ float Qt[64*68];  // [d][s]   (later reused as At[t][s] = probs^T)
  __shared__ float Kt[64*68];  // [d][j]
  __shared__ float V [64*68];  // [t][d]
  __shared__ float SB[64*68];  // scores [i][j], then exp'd values
  int blk=blockIdx.x; int b=blk/NH, h=blk%NH;
  int tid=threadIdx.x;
  for(int idx=tid; idx<4096; idx+=256){
    int s=idx>>6, d=idx&63;
    const float* r = qkv + ((size_t)(b*NLK+s))*1152 + h*NHD + d;
    Qt[d*68+s]=r[0];
    Kt[d*68+s]=r[384];
    V [s*68+d]=r[768];
  }
  __syncthreads();
  // ---- scores: S[i][j] = (sum_d Q[i][d]*K[j][d]) * 0.125
  {
    const int i0 = (tid>>4)*4, j0 = (tid&15)*4;
    float a00=0.f,a01=0.f,a02=0.f,a03=0.f;
    float a10=0.f,a11=0.f,a12=0.f,a13=0.f;
    float a20=0.f,a21=0.f,a22=0.f,a23=0.f;
    float a30=0.f,a31=0.f,a32=0.f,a33=0.f;
#pragma unroll 4
    for(int d=0;d<64;d++){
      float4 qa = *reinterpret_cast<const float4*>(&Qt[d*68+i0]);
      float4 kb = *reinterpret_cast<const float4*>(&Kt[d*68+j0]);
      a00=fmaf(qa.x,kb.x,a00); a01=fmaf(qa.x,kb.y,a01); a02=fmaf(qa.x,kb.z,a02); a03=fmaf(qa.x,kb.w,a03);
      a10=fmaf(qa.y,kb.x,a10); a11=fmaf(qa.y,kb.y,a11); a12=fmaf(qa.y,kb.z,a12); a13=fmaf(qa.y,kb.w,a13);
      a20=fmaf(qa.z,kb.x,a20); a21=fmaf(qa.z,kb.y,a21); a22=fmaf(qa.z,kb.z,a22); a23=fmaf(qa.z,kb.w,a23);
      a30=fmaf(qa.w,kb.x,a30); a31=fmaf(qa.w,kb.y,a31); a32=fmaf(qa.w,kb.z,a32); a33=fmaf(qa.w,kb.w,a33);
    }
    float4 o0 = {a00*0.125f, a01*0.125f, a02*0.125f, a03*0.125f};
    float4 o1 = {a10*0.125f, a11*0.125f, a12*0.125f, a13*0.125f};
    float4 o2 = {a20*0.125f, a21*0.125f, a22*0.125f, a23*0.125f};
    float4 o3 = {a30*0.125f, a31*0.125f, a32*0.125f, a33*0.125f};
    *reinterpret_cast<float4*>(&SB[(i0  )*68+j0]) = o0;
    *reinterpret_cast<float4*>(&SB[(i0+1)*68+j0]) = o1;
    *reinterpret_cast<float4*>(&SB[(i0+2)*68+j0]) = o2;
    *reinterpret_cast<float4*>(&SB[(i0+3)*68+j0]) = o3;
  }
  __syncthreads();
  // ---- softmax per row (sequential, identical op order)
  if(tid<64){
    float* rowp=&SB[tid*68];
    float m=rowp[0];
    for(int j=1;j<64;j++) m=fmaxf(m,rowp[j]);
    float sum=0.0f;
    for(int j=0;j<64;j++){ float e=__expf(rowp[j]-m); rowp[j]=e; sum+=e; }
    for(int j=0;j<64;j++) Qt[j*68+tid] = rowp[j]/sum;   // At[t][s]
  }
  __syncthreads();
  // ---- out: O[s][d] = sum_t A[s][t]*V[t][d]
  {
    const int s0 = (tid>>4)*4, d0 = (tid&15)*4;
    float a00=0.f,a01=0.f,a02=0.f,a03=0.f;
    float a10=0.f,a11=0.f,a12=0.f,a13=0.f;
    float a20=0.f,a21=0.f,a22=0.f,a23=0.f;
    float a30=0.f,a31=0.f,a32=0.f,a33=0.f;
#pragma unroll 4
    for(int t=0;t<64;t++){
      float4 av = *reinterpret_cast<const float4*>(&Qt[t*68+s0]);
      float4 vv = *reinterpret_cast<const float4*>(&V [t*68+d0]);
      a00=fmaf(av.x,vv.x,a00); a01=fmaf(av.x,vv.y,a01); a02=fmaf(av.x,vv.z,a02); a03=fmaf(av.x,vv.w,a03);
      a10=fmaf(av.y,vv.x,a10); a11=fmaf(av.y,vv.y,a11); a12=fmaf(av.y,vv.z,a12); a13=fmaf(av.y,vv.w,a13);
      a20=fmaf(av.z,vv.x,a20); a21=fmaf(av.z,vv.y,a21); a22=fmaf(av.z,vv.z,a22); a23=fmaf(av.z,vv.w,a23);
      a30=fmaf(av.w,vv.x,a30); a31=fmaf(av.w,vv.y,a31); a32=fmaf(av.w,vv.z,a32); a33=fmaf(av.w,vv.w,a33);
    }
    float rr[4][4] = {{a00,a01,a02,a03},{a10,a11,a12,a13},{a20,a21,a22,a23},{a30,a31,a32,a33}};
#pragma unroll
    for(int si=0; si<4; si++){
      ushort4v h4, l4;
#pragma unroll
      for(int di=0; di<4; di++){
        u16 hi,lo; split2(rr[si][di],hi,lo);
        h4[di]=hi; l4[di]=lo;
      }
      size_t o = ((size_t)(b*NLK+s0+si))*ND + h*NHD + d0;
      *reinterpret_cast<ushort4v*>(&ohi[o]) = h4;
      *reinterpret_cast<ushort4v*>(&olo[o]) = l4;
    }
  }
}

// ---------------------------------------------------------------- final LayerNorm (output)
template<bool FINAL>
__global__ __launch_bounds__(128) void k_ln(const float* __restrict__ X,
                                            const void* __restrict__ gb, size_t go,
                                            void* __restrict__ Y,
                                            const int* __restrict__ flag){
  int row=blockIdx.x, tid=threadIdx.x;
  const bool bf = flag[0] != 0;
  const float* x = X + (size_t)row*ND;
  __shared__ float sbuf[2];
  float v0=x[tid], v1=x[tid+128], v2=x[tid+256];
  float s = v0+v1+v2;
  for(int off=32;off;off>>=1) s += __shfl_down(s,off);
  if((tid&63)==0) sbuf[tid>>6]=s;
  __syncthreads();
  float mean = (sbuf[0]+sbuf[1]) * (1.0f/(float)ND);
  __syncthreads();
  float d0=v0-mean, d1=v1-mean, d2=v2-mean;
  s = d0*d0 + d1*d1 + d2*d2;
  for(int off=32;off;off>>=1) s += __shfl_down(s,off);
  if((tid&63)==0) sbuf[tid>>6]=s;
  __syncthreads();
  float var = (sbuf[0]+sbuf[1]) * (1.0f/(float)ND);
  float rstd = 1.0f / sqrtf(var + 1e-5f);
  float o0 = d0*rstd*ldf(gb,go+tid    ,bf) + ldf(gb,go+ND+tid    ,bf);
  float o1 = d1*rstd*ldf(gb,go+tid+128,bf) + ldf(gb,go+ND+tid+128,bf);
  float o2 = d2*rstd*ldf(gb,go+tid+256,bf) + ldf(gb,go+ND+tid+256,bf);
  if(FINAL && bf){
    u16* yo = (u16*)Y + (size_t)row*ND;
    yo[tid]=f2bf(o0); yo[tid+128]=f2bf(o1); yo[tid+256]=f2bf(o2);
  }else{
    float* yo = (float*)Y + (size_t)row*ND;
    yo[tid]=o0; yo[tid+128]=o1; yo[tid+256]=o2;
  }
}

// ---------------------------------------------------------------- host
extern "C" void kernel_launch(void* const* d_in, const int* in_sizes, int n_in,
                              void* d_out, int out_size, void* d_ws, size_t ws_size,
                              hipStream_t stream){
  (void)in_sizes; (void)n_in; (void)out_size;
  const void* pts   = d_in[0];
  const void* noise = d_in[1];
  const void* pe_w1 = d_in[2];
  const void* pe_b1 = d_in[3];
  const void* pe_w2 = d_in[4];
  const void* pe_b2 = d_in[5];
  const void* pe_w3 = d_in[6];
  const void* pe_b3 = d_in[7];
  const void* pos_w1= d_in[8];
  const void* pos_b1= d_in[9];
  const void* pos_w2= d_in[10];
  const void* pos_b2= d_in[11];
  const void* ln1   = d_in[12];
  const void* wqkv  = d_in[13];
  const void* bqkv  = d_in[14];
  const void* wo    = d_in[15];
  const void* bo    = d_in[16];
  const void* ln2   = d_in[17];
  const void* wi    = d_in[18];
  const void* bi    = d_in[19];
  const void* wo2   = d_in[20];
  const void* bo2   = d_in[21];
  const void* lnf   = d_in[22];

  const size_t needed_small = (6711296ull + 16) * 4;            // ~26.9 MB
  if (ws_size < needed_small) return;
  // big path: hoist all 12 layers of transposed weights (2 planes x WT_ELEMS u16)
  const size_t wt_f32_off = 6711312ull;                         // after flag (16B aligned)
  const size_t needed_big = (wt_f32_off + WT_ELEMS) * 4;        // ~112.4 MB
  const bool big = ws_size >= needed_big;

  float* ws   = (float*)d_ws;
  float* h    = ws;                                   // 786432
  u16*  yhi   = (u16*)(ws + 786432);                  // planes 2048x384
  u16*  ylo   = yhi + 786432;
  float* qkvb = ws + 1572864;                         // 2359296 f32
  u16*  athi  = (u16*)(ws + 3932160);                 // planes 2048x384
  u16*  atlo  = athi + 786432;
  u16*  ubhi  = (u16*)(ws + 1572864);                 // planes 2048x1536 (alias qkvb+attb)
  u16*  ublo  = ubhi + 3145728;
  float* xn   = ws + 1572864;                         // pre-loop alias
  float* centers;
  int*   keep;
  int*   flag;
  u16 *wthi, *wtlo;
  if(big){
    centers = ws + 6684672;
    keep    = (int*)(ws + 6709248);
    flag    = (int*)(ws + 6711296);
    wthi    = (u16*)(ws + wt_f32_off);
    wtlo    = wthi + WT_ELEMS;
  }else{
    // small path layout: wt planes (pre + 1 layer slot) then tail buffers
    wthi    = (u16*)(ws + 4718592);                   // 1916928 u16 = 958464 f32
    wtlo    = (u16*)(ws + 5677056);                   // 1916928 u16
    centers = ws + 6832128;                           // 24576
    keep    = (int*)(ws + 6856704);                   // 2048
    flag    = (int*)(ws + 6858752);
    if(ws_size < (6858752ull + 16) * 4) return;
  }

  k_normalize<<<NB, 256, 0, stream>>>(pts, xn, flag);
  // fused FPS + keep + weight transposes (1024 threads)
  {
    int grid = big ? (64 + 144 + 12*1728) : (64 + 144);
    k_fps_trans<<<grid, 1024, 0, stream>>>(xn, centers, noise, keep, pe_w3, pos_w2,
        wqkv, wo, wi, wo2, wthi, wtlo, flag);
  }
  k_knn_embed<<<NB*NLK, 256, 0, stream>>>(xn, centers, keep,
      pe_w1, pe_b1, pe_w2, pe_b2, pos_w1, pos_b1,
      yhi /*mfhi*/, yhi + 2048*256 /*mflo*/, athi /*phhi*/, athi + 2048*128 /*phlo*/, flag);
  k_gemm_mfma<64,0,false,false><<<dim3(6,32), 256, 0, stream>>>(
      yhi, yhi + 2048*256, wthi, wtlo, 0, pe_b3, 0, flag, nullptr, h, nullptr, nullptr, 384, 256);
  k_gemm_mfma<64,0,true ,false><<<dim3(6,32), 256, 0, stream>>>(
      athi, athi + 2048*128, wthi, wtlo, 98304, pos_b2, 0, flag, h, h, nullptr, nullptr, 384, 128);

  for(int l=0; l<NL; l++){
    size_t lb = big ? (PL_PRE + (size_t)l*PL_LAYER) : PL_PRE;
    if(!big){
      k_transpose4<<<1728, 256, 0, stream>>>(wqkv, wo, wi, wo2, l, wthi, wtlo, flag);
    }
    k_ln_split<<<MM, 128, 0, stream>>>(h, ln1, (size_t)l*2*ND, yhi, ylo, flag);
    k_gemm_mfma<64,0,false,false><<<dim3(18,32), 256, 0, stream>>>(
        yhi, ylo, wthi, wtlo, lb, bqkv, (size_t)l*1152, flag, nullptr, qkvb, nullptr, nullptr, 1152, 384);
    k_attn_pl<<<NB*NH, 256, 0, stream>>>(qkvb, athi, atlo);
    k_gemm_mfma<64,0,true ,false><<<dim3(6,32), 256, 0, stream>>>(
        athi, atlo, wthi, wtlo, lb + 442368, bo, (size_t)l*384, flag, h, h, nullptr, nullptr, 384, 384);
    k_ln_split<<<MM, 128, 0, stream>>>(h, ln2, (size_t)l*2*ND, yhi, ylo, flag);
    k_gemm_mfma<64,1,false,true ><<<dim3(24,32), 256, 0, stream>>>(
        yhi, ylo, wthi, wtlo, lb + 589824, bi, (size_t)l*1536, flag, nullptr, nullptr, ubhi, ublo, 1536, 384);
    k_gemm_mfma<64,0,true ,false><<<dim3(6,32), 256, 0, stream>>>(
        ubhi, ublo, wthi, wtlo, lb + 1179648, bo2, (size_t)l*384, flag, h, h, nullptr, nullptr, 384, 1536);
  }
  k_ln<true><<<MM, 128, 0, stream>>>(h, lnf, 0, d_out, flag);
}

// Round 12
// 1692.927 us; speedup vs baseline: 1.0178x; 1.0178x over previous
//
#include <hip/hip_runtime.h>

// Problem constants
#define NPTS 8192
#define NB   32
#define NG   256
#define NK   32
#define ND   384
#define NH   6
#define NLK  64
#define NF   1536
#define NHD  64
#define NL   12
#define MM   2048   // NB*NLK token rows

typedef unsigned short u16;
typedef unsigned long long u64;
typedef __attribute__((ext_vector_type(8))) short short8;    // bf16x8 MFMA frag
typedef __attribute__((ext_vector_type(16))) float f32x16;   // 32x32 MFMA acc
typedef __attribute__((ext_vector_type(4))) unsigned short ushort4v;

// per-layer transposed-weight plane layout (element offsets within one plane)
#define PL_PRE   147456ull          // pe_w3 (98304) + pos_w2 (49152)
#define PL_LAYER 1769472ull         // qkv|wo|wi|wo2 for one layer
#define WT_ELEMS (PL_PRE + 12ull*PL_LAYER)   // 21381120 u16 per plane

__device__ __forceinline__ float bf2f(u16 v){
  unsigned int u = ((unsigned int)v) << 16;
  float f; __builtin_memcpy(&f, &u, 4); return f;
}
__device__ __forceinline__ float ldf(const void* p, size_t i, bool bf){
  if(bf) return bf2f(((const u16*)p)[i]);
  return ((const float*)p)[i];
}
__device__ __forceinline__ u16 f2bf(float f){
  unsigned int x; __builtin_memcpy(&x, &f, 4);
  x += 0x7fffu + ((x >> 16) & 1u);
  return (u16)(x >> 16);
}
// split f32 -> (hi, lo) bf16 planes; hi RNE, lo = RNE(residual)
__device__ __forceinline__ void split2(float v, u16& hi, u16& lo){
  hi = f2bf(v);
  lo = f2bf(v - bf2f(hi));
}

// ---------------------------------------------------------------- normalize (+ inline dtype detect)
__device__ __forceinline__ float blockMax256(float v, float* sb, int tid){
  for(int off=32; off; off>>=1) v = fmaxf(v, __shfl_down(v, off));
  __syncthreads();
  if((tid&63)==0) sb[tid>>6] = v;
  __syncthreads();
  return fmaxf(fmaxf(sb[0],sb[1]), fmaxf(sb[2],sb[3]));
}

__global__ __launch_bounds__(256) void k_normalize(const void* __restrict__ pts,
                                                   float* __restrict__ xn,
                                                   int* __restrict__ flag){
#pragma clang fp contract(off)
  int b = blockIdx.x, tid = threadIdx.x;
  __shared__ float sb[4];
  __shared__ int sbad;
  if(tid==0) sbad = 0;
  __syncthreads();
  {
    const u16* p16 = (const u16*)pts;
    int hit=0;
    for(int i=tid; i<4096; i+=256){
      unsigned e = (p16[i] >> 7) & 0xFFu;
      if(e >= 0x90u) hit=1;
    }
    if(hit) atomicOr(&sbad, 1);
  }
  __syncthreads();
  const bool bf = (sbad == 0);     // 1 = bf16, 0 = f32
  if(b==0 && tid==0) flag[0] = bf ? 1 : 0;
  const size_t base = (size_t)b*NPTS*3;
  float mn0=1e30f,mn1=1e30f,mn2=1e30f, mx0=-1e30f,mx1=-1e30f,mx2=-1e30f;
  for(int n=tid; n<NPTS; n+=256){
    float x0=ldf(pts,base+n*3,bf), x1=ldf(pts,base+n*3+1,bf), x2=ldf(pts,base+n*3+2,bf);
    mn0=fminf(mn0,x0); mx0=fmaxf(mx0,x0);
    mn1=fminf(mn1,x1); mx1=fmaxf(mx1,x1);
    mn2=fminf(mn2,x2); mx2=fmaxf(mx2,x2);
  }
  mx0=blockMax256(mx0,sb,tid); mn0=-blockMax256(-mn0,sb,tid);
  mx1=blockMax256(mx1,sb,tid); mn1=-blockMax256(-mn1,sb,tid);
  mx2=blockMax256(mx2,sb,tid); mn2=-blockMax256(-mn2,sb,tid);
  float c0=0.5f*(mn0+mx0), c1=0.5f*(mn1+mx1), c2=0.5f*(mn2+mx2);
  float mr=0.0f;
  for(int n=tid; n<NPTS; n+=256){
    float d0=ldf(pts,base+n*3,bf)-c0, d1=ldf(pts,base+n*3+1,bf)-c1, d2=ldf(pts,base+n*3+2,bf)-c2;
    float nr = sqrtf((d0*d0 + d1*d1) + d2*d2);
    mr = fmaxf(mr, nr);
  }
  float radius = blockMax256(mr, sb, tid);
  float* XO = xn + base;
  for(int n=tid; n<NPTS; n+=256){
    XO[n*3  ] = (ldf(pts,base+n*3  ,bf)-c0)/radius;
    XO[n*3+1] = (ldf(pts,base+n*3+1,bf)-c1)/radius;
    XO[n*3+2] = (ldf(pts,base+n*3+2,bf)-c2)/radius;
  }
}

// ---------------------------------------------------------------- fused FPS + keep + weight transposes
// R9 proven config: 512 threads (1024 regressed in R11: barrier/reduce cost
// grows with wave count; fps is sync-bound per round, not chain-bound).
__device__ __forceinline__ void kmax_dpp_step(unsigned& hi, unsigned& lo, unsigned oh, unsigned ol){
  bool g = (oh > hi) || (oh == hi && ol > lo);
  hi = g ? oh : hi; lo = g ? ol : lo;
}
#define KMAX_DPP(CTRL) { \
  unsigned oh=(unsigned)__builtin_amdgcn_update_dpp(0,(int)kh,(CTRL),0xf,0xf,true); \
  unsigned ol=(unsigned)__builtin_amdgcn_update_dpp(0,(int)kl,(CTRL),0xf,0xf,true); \
  kmax_dpp_step(kh,kl,oh,ol); }

__global__ __launch_bounds__(512) void k_fps_trans(
    const float* __restrict__ xn, float* __restrict__ centers,
    const void* __restrict__ noise, int* __restrict__ keep,
    const void* __restrict__ pe_w3, const void* __restrict__ pos_w2,
    const void* __restrict__ wqkv, const void* __restrict__ wo,
    const void* __restrict__ wi,   const void* __restrict__ wo2,
    u16* __restrict__ wthi, u16* __restrict__ wtlo,
    const int* __restrict__ flag)
{
  __shared__ float xs[NPTS*3];   // 96 KB coord mirror (fps) / transpose tile / noise buf
  __shared__ u64 skey[3];
  __shared__ int sc[NG];
  int tid = threadIdx.x;

  if(blockIdx.x >= 64){
    // ---------------- transpose path (512 threads) ----------------
    const bool bf = flag[0]!=0;
    float (*t)[33] = reinterpret_cast<float(*)[33]>(xs);
    int gid = blockIdx.x - 64;
    const void* W; int Kd, Nd; size_t woff, doff; int local;
    if(gid < 96){        W=pe_w3;  Kd=256; Nd=384; woff=0; doff=0;      local=gid; }
    else if(gid < 144){  W=pos_w2; Kd=128; Nd=384; woff=0; doff=98304;  local=gid-96; }
    else{
      int g2 = gid - 144; int l = g2 / 1728; int id = g2 % 1728;
      size_t lb = PL_PRE + (size_t)l*PL_LAYER;
      if(id < 432){        W=wqkv; Kd=384;  Nd=1152; woff=(size_t)l*442368; doff=lb;          local=id; }
      else if(id < 576){   W=wo;   Kd=384;  Nd=384;  woff=(size_t)l*147456; doff=lb+442368;   local=id-432; }
      else if(id < 1152){  W=wi;   Kd=384;  Nd=1536; woff=(size_t)l*589824; doff=lb+589824;   local=id-576; }
      else {               W=wo2;  Kd=1536; Nd=384;  woff=(size_t)l*589824; doff=lb+1179648;  local=id-1152; }
    }
    int ntiles = Nd >> 5;
    int n0 = (local % ntiles)*32, k0 = (local / ntiles)*32;
    for(int i=0;i<2;i++){
      int idx = tid + i*512; int kr = idx>>5, nc = idx&31;
      t[kr][nc] = ldf(W, woff + (size_t)(k0+kr)*Nd + n0+nc, bf);
    }
    __syncthreads();
    for(int i=0;i<2;i++){
      int idx = tid + i*512; int nr = idx>>5, kc = idx&31;
      float v = t[kc][nr];
      u16 hi,lo; split2(v,hi,lo);
      size_t o = doff + (size_t)(n0+nr)*Kd + k0+kc;
      wthi[o]=hi; wtlo[o]=lo;
    }
    return;
  }

  if(blockIdx.x >= 32){
    // ---------------- keep path (rank of noise per batch) ----------------
    const bool bf = flag[0]!=0;
    int b = blockIdx.x - 32;
    float* nv = xs;
    if(tid < NG) nv[tid] = ldf(noise, (size_t)b*NG+tid, bf);
    __syncthreads();
    if(tid < NG){
      float v = nv[tid]; int r = 0;
      for(int j=0; j<NG; j++){
        float u = nv[j];
        r += (u < v) || (u == v && j < tid);
      }
      if(r < NLK) keep[b*NLK + r] = tid;
    }
    return;
  }

  // ---------------- FPS path (identical math to R9) ----------------
  {
#pragma clang fp contract(off)
    int b = blockIdx.x;
    int lane = tid & 63;
    const float* X = xn + (size_t)b*NPTS*3;
    float px[16],py[16],pz[16],dd[16];
#pragma unroll
    for(int s=0;s<16;s++){
      int n = s*512 + tid;
      px[s]=X[n*3]; py[s]=X[n*3+1]; pz[s]=X[n*3+2];
      dd[s]=1e10f;
    }
    for(int i=tid; i<NPTS*3; i+=512) xs[i] = X[i];
    if(tid==0){ skey[0]=0ull; skey[1]=0ull; skey[2]=0ull; sc[0]=0; }
    __syncthreads();
    float lx = xs[0], ly = xs[1], lz = xs[2];
    for(int i=1;i<NG;i++){
      int c = i % 3;
      float bv=-1.0f; int bs=0;
#pragma unroll
      for(int s=0;s<16;s++){
        float dx=px[s]-lx, dy=py[s]-ly, dz=pz[s]-lz;
        float d=(dx*dx + dy*dy) + dz*dz;
        d = fminf(dd[s], d); dd[s]=d;
        if(d > bv){ bv=d; bs=s; }   // strict >: first index on ties
      }
      int bn = bs*512 + tid;
      unsigned kh; __builtin_memcpy(&kh,&bv,4);
      unsigned kl = (unsigned)(NPTS-1-bn);
      KMAX_DPP(0x111)
      KMAX_DPP(0x112)
      KMAX_DPP(0x114)
      KMAX_DPP(0x118)
      KMAX_DPP(0x142)
      KMAX_DPP(0x143)
      if(lane==63) atomicMax(&skey[c], ((u64)kh<<32) | (u64)kl);
      __syncthreads();
      u64 k64 = skey[c];
      int n = (NPTS-1) - (int)(k64 & 0xFFFFFFFFull);
      n &= (NPTS-1);
      if(tid==0){ sc[i]=n; skey[(i+2)%3]=0ull; }
      lx = xs[n*3]; ly = xs[n*3+1]; lz = xs[n*3+2];
    }
    __syncthreads();
    if(tid < NG){
      int n = sc[tid] & (NPTS-1);
      centers[((size_t)b*NG+tid)*3  ] = xs[n*3];
      centers[((size_t)b*NG+tid)*3+1] = xs[n*3+1];
      centers[((size_t)b*NG+tid)*3+2] = xs[n*3+2];
    }
  }
}

// ---------------------------------------------------------------- fused kNN + embed (same grid/block mapping)
__global__ __launch_bounds__(256) void k_knn_embed(
    const float* __restrict__ xn, const float* __restrict__ centers,
    const int* __restrict__ keep,
    const void* __restrict__ w1, const void* __restrict__ b1,
    const void* __restrict__ w2, const void* __restrict__ b2,
    const void* __restrict__ pw1, const void* __restrict__ pb1,
    u16* __restrict__ mfhi, u16* __restrict__ mflo,
    u16* __restrict__ phhi, u16* __restrict__ phlo,
    const int* __restrict__ flag)
{
  int blk=blockIdx.x; int b=blk>>6; int j=blk&63; int tid=threadIdx.x;
  const bool bf = flag[0] != 0;
  __shared__ __align__(16) float sd[NPTS];   // 32KB; reused as f1t (128*36 floats) in embed
  __shared__ int   sel[NK];
  __shared__ float rv[4]; __shared__ int rn[4];
  __shared__ int   sseln;
  __shared__ float pat[NK*3];
  int g = keep[b*NLK + j] & (NG-1);
  const float* C = centers + ((size_t)b*NG + g)*3;
  float c0=C[0], c1=C[1], c2=C[2];
  const float* X = xn + (size_t)b*NPTS*3;
  {
#pragma clang fp contract(off)
    float cc = (c0*c0 + c1*c1) + c2*c2;
    for(int n=tid; n<NPTS; n+=256){
      float x0=X[n*3], x1=X[n*3+1], x2=X[n*3+2];
      float xx=(x0*x0 + x1*x1) + x2*x2;
      float dt=(c0*x0 + c1*x1) + c2*x2;
      sd[n] = (cc + xx) - 2.0f*dt;
    }
  }
  __syncthreads();
  float dl[32];
  for(int s=0;s<32;s++) dl[s] = sd[s*256 + tid];
  unsigned int alive = 0xffffffffu;
  for(int r=0; r<NK; r++){
    float bv=1e30f; int bn=0x7fffffff;
    for(int s=0;s<32;s++){
      if(alive & (1u<<s)){
        float v = dl[s];
        if(v < bv){ bv=v; bn=s*256+tid; }
      }
    }
    for(int off=32;off;off>>=1){
      float ov=__shfl_down(bv,off); int on=__shfl_down(bn,off);
      if(ov<bv || (ov==bv && on<bn)){ bv=ov; bn=on; }
    }
    if((tid&63)==0){ rv[tid>>6]=bv; rn[tid>>6]=bn; }
    __syncthreads();
    if(tid==0){
      float v=rv[0]; int n=rn[0];
      for(int w=1;w<4;w++) if(rv[w]<v || (rv[w]==v && rn[w]<n)){ v=rv[w]; n=rn[w]; }
      n &= (NPTS-1);
      sseln=n; sel[r]=n;
    }
    __syncthreads();
    int n = sseln;
    if((n & 255) == tid) alive &= ~(1u << (n >> 8));
  }
  __syncthreads();
  if(tid < NK){
    int n = sel[tid] & (NPTS-1);
    pat[tid*3+0] = X[n*3  ]-c0;
    pat[tid*3+1] = X[n*3+1]-c1;
    pat[tid*3+2] = X[n*3+2]-c2;
  }
  __syncthreads();
  // ---------------- embed part (sd reused as f1t) ----------------
  float* f1t = sd;                 // [jj][k], pitch 36; 4608 floats < 8192
  int row = b*NLK + j;
  for(int i=0;i<16;i++){
    int idx = tid + i*256;
    int k = idx>>7, m = idx&127;
    float v = ldf(b1,m,bf)
            + pat[k*3+0]*ldf(w1,        m,bf)
            + pat[k*3+1]*ldf(w1, 128 + m,bf)
            + pat[k*3+2]*ldf(w1, 256 + m,bf);
    f1t[m*36 + k] = fmaxf(v, 0.0f);
  }
  __syncthreads();
  float acc[NK];
  {
    float bv = ldf(b2, tid, bf);
#pragma unroll
    for(int k=0;k<NK;k++) acc[k]=bv;
  }
  for(int jj=0;jj<128;jj++){
    float wv = ldf(w2, (size_t)jj*256+tid, bf);
    const float* fr = &f1t[jj*36];
#pragma unroll
    for(int k8=0;k8<8;k8++){
      float4 fv = *reinterpret_cast<const float4*>(fr + k8*4);
      acc[k8*4+0] = fmaf(fv.x, wv, acc[k8*4+0]);
      acc[k8*4+1] = fmaf(fv.y, wv, acc[k8*4+1]);
      acc[k8*4+2] = fmaf(fv.z, wv, acc[k8*4+2]);
      acc[k8*4+3] = fmaf(fv.w, wv, acc[k8*4+3]);
    }
  }
  float mx = acc[0];
#pragma unroll
  for(int k=1;k<NK;k++) mx = fmaxf(mx, acc[k]);
  { u16 hi,lo; split2(mx,hi,lo);
    mfhi[(size_t)row*256 + tid]=hi; mflo[(size_t)row*256 + tid]=lo; }
  if(tid < 128){
    float v = ldf(pb1,tid,bf)
            + c0*ldf(pw1,        tid,bf)
            + c1*ldf(pw1, 128 + tid,bf)
            + c2*ldf(pw1, 256 + tid,bf);
    v = fmaxf(v, 0.0f);
    u16 hi,lo; split2(v,hi,lo);
    phhi[(size_t)row*128 + tid]=hi; phlo[(size_t)row*128 + tid]=lo;
  }
}

// ---------------------------------------------------------------- batched per-layer transpose (fallback path only)
__global__ __launch_bounds__(256) void k_transpose4(
    const void* __restrict__ wqkv, const void* __restrict__ wo,
    const void* __restrict__ wi,   const void* __restrict__ wo2,
    int l, u16* __restrict__ dhi, u16* __restrict__ dlo,
    const int* __restrict__ flag){
  __shared__ float t[32][33];
  const bool bf = flag[0]!=0;
  int id = blockIdx.x;
  const void* W; int Kd, Nd; size_t woff, doff; int local;
  if(id < 432){        W=wqkv; Kd=384;  Nd=1152; woff=(size_t)l*442368; doff=PL_PRE;          local=id; }
  else if(id < 576){   W=wo;   Kd=384;  Nd=384;  woff=(size_t)l*147456; doff=PL_PRE+442368;   local=id-432; }
  else if(id < 1152){  W=wi;   Kd=384;  Nd=1536; woff=(size_t)l*589824; doff=PL_PRE+589824;   local=id-576; }
  else {               W=wo2;  Kd=1536; Nd=384;  woff=(size_t)l*589824; doff=PL_PRE+1179648;  local=id-1152; }
  int ntiles = Nd >> 5;
  int n0 = (local % ntiles)*32, k0 = (local / ntiles)*32;
  for(int i=0;i<4;i++){
    int idx = threadIdx.x + i*256; int kr = idx>>5, nc = idx&31;
    t[kr][nc] = ldf(W, woff + (size_t)(k0+kr)*Nd + n0+nc, bf);
  }
  __syncthreads();
  for(int i=0;i<4;i++){
    int idx = threadIdx.x + i*256; int nr = idx>>5, kc = idx&31;
    float v = t[kc][nr];
    u16 hi,lo; split2(v,hi,lo);
    size_t o = doff + (size_t)(n0+nr)*Kd + k0+kc;
    dhi[o]=hi; dlo[o]=lo;
  }
}

// ---------------------------------------------------------------- LayerNorm -> bf16 hi/lo planes
__global__ __launch_bounds__(128) void k_ln_split(const float* __restrict__ X,
                                                  const void* __restrict__ gb, size_t go,
                                                  u16* __restrict__ Yhi, u16* __restrict__ Ylo,
                                                  const int* __restrict__ flag){
  int row=blockIdx.x, tid=threadIdx.x;
  const bool bf = flag[0] != 0;
  const float* x = X + (size_t)row*ND;
  __shared__ float sbuf[2];
  float v0=x[tid], v1=x[tid+128], v2=x[tid+256];
  float s = v0+v1+v2;
  for(int off=32;off;off>>=1) s += __shfl_down(s,off);
  if((tid&63)==0) sbuf[tid>>6]=s;
  __syncthreads();
  float mean = (sbuf[0]+sbuf[1]) * (1.0f/(float)ND);
  __syncthreads();
  float d0=v0-mean, d1=v1-mean, d2=v2-mean;
  s = d0*d0 + d1*d1 + d2*d2;
  for(int off=32;off;off>>=1) s += __shfl_down(s,off);
  if((tid&63)==0) sbuf[tid>>6]=s;
  __syncthreads();
  float var = (sbuf[0]+sbuf[1]) * (1.0f/(float)ND);
  float rstd = 1.0f / sqrtf(var + 1e-5f);
  float o0 = d0*rstd*ldf(gb,go+tid    ,bf) + ldf(gb,go+ND+tid    ,bf);
  float o1 = d1*rstd*ldf(gb,go+tid+128,bf) + ldf(gb,go+ND+tid+128,bf);
  float o2 = d2*rstd*ldf(gb,go+tid+256,bf) + ldf(gb,go+ND+tid+256,bf);
  u16 hi,lo; size_t rb = (size_t)row*ND;
  split2(o0,hi,lo); Yhi[rb+tid    ]=hi; Ylo[rb+tid    ]=lo;
  split2(o1,hi,lo); Yhi[rb+tid+128]=hi; Ylo[rb+tid+128]=lo;
  split2(o2,hi,lo); Yhi[rb+tid+256]=hi; Ylo[rb+tid+256]=lo;
}

// ---------------------------------------------------------------- MFMA GEMM, bf16x3 split precision, 32x32x16
// R9 proven config: TM=64, 256 thr, reg-staged, 2-deep named prefetch,
// one barrier/K-step.
template<int TM, int ACT, bool RES, bool OSPLIT>
__global__ __launch_bounds__(256) void k_gemm_mfma(
    const u16* __restrict__ Ahi, const u16* __restrict__ Alo,
    const u16* __restrict__ Whi, const u16* __restrict__ Wlo, size_t wo,
    const void* __restrict__ bias, size_t bo, const int* __restrict__ flag,
    const float* __restrict__ res, float* __restrict__ Cf,
    u16* __restrict__ Ohi, u16* __restrict__ Olo,
    int N, int K)
{
  constexpr int TN = 64;
  __shared__ __align__(16) u16 sAh[2][TM*40];
  __shared__ __align__(16) u16 sAl[2][TM*40];
  __shared__ __align__(16) u16 sBh[2][TN*40];
  __shared__ __align__(16) u16 sBl[2][TN*40];
  int tid = threadIdx.x;
  int wave = tid >> 6, lane = tid & 63;
  int wm = wave >> 1, wn = wave & 1;
  int l31 = lane & 31, half = lane >> 5;
  int row0 = blockIdx.y*TM, col0 = blockIdx.x*TN;
  const bool bf = flag[0] != 0;
  f32x16 acc;
#pragma unroll
  for(int r=0;r<16;r++) acc[r]=0.f;

  const int sr  = tid >> 2;
  const int scc = (tid & 3) * 8;
  const u16* gAh = Ahi + (size_t)(row0+sr)*K + scc;
  const u16* gAl = Alo + (size_t)(row0+sr)*K + scc;
  const u16* gBh = Whi + wo + (size_t)(col0+sr)*K + scc;
  const u16* gBl = Wlo + wo + (size_t)(col0+sr)*K + scc;
  const int ldst = sr*40 + scc;

  // two named prefetch sets (set0 = even K-steps, set1 = odd)
  uint4 rah0 = *reinterpret_cast<const uint4*>(gAh);
  uint4 ral0 = *reinterpret_cast<const uint4*>(gAl);
  uint4 rbh0 = *reinterpret_cast<const uint4*>(gBh);
  uint4 rbl0 = *reinterpret_cast<const uint4*>(gBl);
  uint4 rah1 = *reinterpret_cast<const uint4*>(gAh + 32);
  uint4 ral1 = *reinterpret_cast<const uint4*>(gAl + 32);
  uint4 rbh1 = *reinterpret_cast<const uint4*>(gBh + 32);
  uint4 rbl1 = *reinterpret_cast<const uint4*>(gBl + 32);

  const int nk = K >> 5;   // even for all instantiations (K in {128,256,384,1536})

#define GEMM_STEP(S, TT) { \
    *reinterpret_cast<uint4*>(&sAh[S][ldst]) = rah##S; \
    *reinterpret_cast<uint4*>(&sAl[S][ldst]) = ral##S; \
    *reinterpret_cast<uint4*>(&sBh[S][ldst]) = rbh##S; \
    *reinterpret_cast<uint4*>(&sBl[S][ldst]) = rbl##S; \
    __syncthreads(); \
    if((TT)+2 < nk){ \
      const int ko = ((TT)+2) << 5; \
      rah##S = *reinterpret_cast<const uint4*>(gAh + ko); \
      ral##S = *reinterpret_cast<const uint4*>(gAl + ko); \
      rbh##S = *reinterpret_cast<const uint4*>(gBh + ko); \
      rbl##S = *reinterpret_cast<const uint4*>(gBl + ko); \
    } \
    _Pragma("unroll") \
    for(int ks=0; ks<2; ks++){ \
      int aoff = (wm*32 + l31)*40 + ks*16 + half*8; \
      int boff = (wn*32 + l31)*40 + ks*16 + half*8; \
      short8 ah = *reinterpret_cast<const short8*>(&sAh[S][aoff]); \
      short8 al = *reinterpret_cast<const short8*>(&sAl[S][aoff]); \
      short8 bh = *reinterpret_cast<const short8*>(&sBh[S][boff]); \
      short8 bl = *reinterpret_cast<const short8*>(&sBl[S][boff]); \
      acc = __builtin_amdgcn_mfma_f32_32x32x16_bf16(ah, bh, acc, 0,0,0); \
      acc = __builtin_amdgcn_mfma_f32_32x32x16_bf16(ah, bl, acc, 0,0,0); \
      acc = __builtin_amdgcn_mfma_f32_32x32x16_bf16(al, bh, acc, 0,0,0); \
    } \
  }

  for(int t=0; t<nk; t+=2){
    GEMM_STEP(0, t)
    GEMM_STEP(1, t+1)
  }
#undef GEMM_STEP

  int col = col0 + wn*32 + l31;
  float bv = ldf(bias, bo+col, bf);
#pragma unroll
  for(int r=0;r<16;r++){
    int row = row0 + wm*32 + (r&3) + 8*(r>>2) + 4*half;
    float v = acc[r] + bv;
    if(ACT==1){
      float xx = v;
      v = 0.5f*xx*(1.0f + tanhf(0.7978845608028654f*(xx + 0.044715f*xx*xx*xx)));
    }
    if(RES) v += res[(size_t)row*N + col];
    if(OSPLIT){
      u16 hi,lo; split2(v,hi,lo);
      Ohi[(size_t)row*N + col]=hi; Olo[(size_t)row*N + col]=lo;
    }else{
      Cf[(size_t)row*N + col]=v;
    }
  }
}

// ---------------------------------------------------------------- attention (f32 math, register-tiled) -> bf16 planes
__global__ __launch_bounds__(256) void k_attn_pl(const float* __restrict__ qkv,
                                                 u16* __restrict__ ohi,
                                                 u16* __restrict__ olo){
  __shared__ float Qt[64*68];  // [d][s]   (later reused as At[t][s] = probs^T)
  __shared__ float Kt[64*68];  // [d][j]
  __shared__ float V [64*68];  // [t][d]
  __shared__ float SB[64*68];  // scores [i][j], then exp'd values
  int blk=blockIdx.x; int b=blk/NH, h=blk%NH;
  int tid=threadIdx.x;
  for(int idx=tid; idx<4096; idx+=256){
    int s=idx>>6, d=idx&63;
    const float* r = qkv + ((size_t)(b*NLK+s))*1152 + h*NHD + d;
    Qt[d*68+s]=r[0];
    Kt[d*68+s]=r[384];
    V [s*68+d]=r[768];
  }
  __syncthreads();
  // ---- scores: S[i][j] = (sum_d Q[i][d]*K[j][d]) * 0.125
  {
    const int i0 = (tid>>4)*4, j0 = (tid&15)*4;
    float a00=0.f,a01=0.f,a02=0.f,a03=0.f;
    float a10=0.f,a11=0.f,a12=0.f,a13=0.f;
    float a20=0.f,a21=0.f,a22=0.f,a23=0.f;
    float a30=0.f,a31=0.f,a32=0.f,a33=0.f;
#pragma unroll 4
    for(int d=0;d<64;d++){
      float4 qa = *reinterpret_cast<const float4*>(&Qt[d*68+i0]);
      float4 kb = *reinterpret_cast<const float4*>(&Kt[d*68+j0]);
      a00=fmaf(qa.x,kb.x,a00); a01=fmaf(qa.x,kb.y,a01); a02=fmaf(qa.x,kb.z,a02); a03=fmaf(qa.x,kb.w,a03);
      a10=fmaf(qa.y,kb.x,a10); a11=fmaf(qa.y,kb.y,a11); a12=fmaf(qa.y,kb.z,a12); a13=fmaf(qa.y,kb.w,a13);
      a20=fmaf(qa.z,kb.x,a20); a21=fmaf(qa.z,kb.y,a21); a22=fmaf(qa.z,kb.z,a22); a23=fmaf(qa.z,kb.w,a23);
      a30=fmaf(qa.w,kb.x,a30); a31=fmaf(qa.w,kb.y,a31); a32=fmaf(qa.w,kb.z,a32); a33=fmaf(qa.w,kb.w,a33);
    }
    float4 o0 = {a00*0.125f, a01*0.125f, a02*0.125f, a03*0.125f};
    float4 o1 = {a10*0.125f, a11*0.125f, a12*0.125f, a13*0.125f};
    float4 o2 = {a20*0.125f, a21*0.125f, a22*0.125f, a23*0.125f};
    float4 o3 = {a30*0.125f, a31*0.125f, a32*0.125f, a33*0.125f};
    *reinterpret_cast<float4*>(&SB[(i0  )*68+j0]) = o0;
    *reinterpret_cast<float4*>(&SB[(i0+1)*68+j0]) = o1;
    *reinterpret_cast<float4*>(&SB[(i0+2)*68+j0]) = o2;
    *reinterpret_cast<float4*>(&SB[(i0+3)*68+j0]) = o3;
  }
  __syncthreads();
  // ---- softmax per row (sequential, identical op order)
  if(tid<64){
    float* rowp=&SB[tid*68];
    float m=rowp[0];
    for(int j=1;j<64;j++) m=fmaxf(m,rowp[j]);
    float sum=0.0f;
    for(int j=0;j<64;j++){ float e=__expf(rowp[j]-m); rowp[j]=e; sum+=e; }
    for(int j=0;j<64;j++) Qt[j*68+tid] = rowp[j]/sum;   // At[t][s]
  }
  __syncthreads();
  // ---- out: O[s][d] = sum_t A[s][t]*V[t][d]
  {
    const int s0 = (tid>>4)*4, d0 = (tid&15)*4;
    float a00=0.f,a01=0.f,a02=0.f,a03=0.f;
    float a10=0.f,a11=0.f,a12=0.f,a13=0.f;
    float a20=0.f,a21=0.f,a22=0.f,a23=0.f;
    float a30=0.f,a31=0.f,a32=0.f,a33=0.f;
#pragma unroll 4
    for(int t=0;t<64;t++){
      float4 av = *reinterpret_cast<const float4*>(&Qt[t*68+s0]);
      float4 vv = *reinterpret_cast<const float4*>(&V [t*68+d0]);
      a00=fmaf(av.x,vv.x,a00); a01=fmaf(av.x,vv.y,a01); a02=fmaf(av.x,vv.z,a02); a03=fmaf(av.x,vv.w,a03);
      a10=fmaf(av.y,vv.x,a10); a11=fmaf(av.y,vv.y,a11); a12=fmaf(av.y,vv.z,a12); a13=fmaf(av.y,vv.w,a13);
      a20=fmaf(av.z,vv.x,a20); a21=fmaf(av.z,vv.y,a21); a22=fmaf(av.z,vv.z,a22); a23=fmaf(av.z,vv.w,a23);
      a30=fmaf(av.w,vv.x,a30); a31=fmaf(av.w,vv.y,a31); a32=fmaf(av.w,vv.z,a32); a33=fmaf(av.w,vv.w,a33);
    }
    float rr[4][4] = {{a00,a01,a02,a03},{a10,a11,a12,a13},{a20,a21,a22,a23},{a30,a31,a32,a33}};
#pragma unroll
    for(int si=0; si<4; si++){
      ushort4v h4, l4;
#pragma unroll
      for(int di=0; di<4; di++){
        u16 hi,lo; split2(rr[si][di],hi,lo);
        h4[di]=hi; l4[di]=lo;
      }
      size_t o = ((size_t)(b*NLK+s0+si))*ND + h*NHD + d0;
      *reinterpret_cast<ushort4v*>(&ohi[o]) = h4;
      *reinterpret_cast<ushort4v*>(&olo[o]) = l4;
    }
  }
}

// ---------------------------------------------------------------- final LayerNorm (output)
template<bool FINAL>
__global__ __launch_bounds__(128) void k_ln(const float* __restrict__ X,
                                            const void* __restrict__ gb, size_t go,
                                            void* __restrict__ Y,
                                            const int* __restrict__ flag){
  int row=blockIdx.x, tid=threadIdx.x;
  const bool bf = flag[0] != 0;
  const float* x = X + (size_t)row*ND;
  __shared__ float sbuf[2];
  float v0=x[tid], v1=x[tid+128], v2=x[tid+256];
  float s = v0+v1+v2;
  for(int off=32;off;off>>=1) s += __shfl_down(s,off);
  if((tid&63)==0) sbuf[tid>>6]=s;
  __syncthreads();
  float mean = (sbuf[0]+sbuf[1]) * (1.0f/(float)ND);
  __syncthreads();
  float d0=v0-mean, d1=v1-mean, d2=v2-mean;
  s = d0*d0 + d1*d1 + d2*d2;
  for(int off=32;off;off>>=1) s += __shfl_down(s,off);
  if((tid&63)==0) sbuf[tid>>6]=s;
  __syncthreads();
  float var = (sbuf[0]+sbuf[1]) * (1.0f/(float)ND);
  float rstd = 1.0f / sqrtf(var + 1e-5f);
  float o0 = d0*rstd*ldf(gb,go+tid    ,bf) + ldf(gb,go+ND+tid    ,bf);
  float o1 = d1*rstd*ldf(gb,go+tid+128,bf) + ldf(gb,go+ND+tid+128,bf);
  float o2 = d2*rstd*ldf(gb,go+tid+256,bf) + ldf(gb,go+ND+tid+256,bf);
  if(FINAL && bf){
    u16* yo = (u16*)Y + (size_t)row*ND;
    yo[tid]=f2bf(o0); yo[tid+128]=f2bf(o1); yo[tid+256]=f2bf(o2);
  }else{
    float* yo = (float*)Y + (size_t)row*ND;
    yo[tid]=o0; yo[tid+128]=o1; yo[tid+256]=o2;
  }
}

// ---------------------------------------------------------------- host
extern "C" void kernel_launch(void* const* d_in, const int* in_sizes, int n_in,
                              void* d_out, int out_size, void* d_ws, size_t ws_size,
                              hipStream_t stream){
  (void)in_sizes; (void)n_in; (void)out_size;
  const void* pts   = d_in[0];
  const void* noise = d_in[1];
  const void* pe_w1 = d_in[2];
  const void* pe_b1 = d_in[3];
  const void* pe_w2 = d_in[4];
  const void* pe_b2 = d_in[5];
  const void* pe_w3 = d_in[6];
  const void* pe_b3 = d_in[7];
  const void* pos_w1= d_in[8];
  const void* pos_b1= d_in[9];
  const void* pos_w2= d_in[10];
  const void* pos_b2= d_in[11];
  const void* ln1   = d_in[12];
  const void* wqkv  = d_in[13];
  const void* bqkv  = d_in[14];
  const void* wo    = d_in[15];
  const void* bo    = d_in[16];
  const void* ln2   = d_in[17];
  const void* wi    = d_in[18];
  const void* bi    = d_in[19];
  const void* wo2   = d_in[20];
  const void* bo2   = d_in[21];
  const void* lnf   = d_in[22];

  const size_t needed_small = (6711296ull + 16) * 4;            // ~26.9 MB
  if (ws_size < needed_small) return;
  // big path: hoist all 12 layers of transposed weights (2 planes x WT_ELEMS u16)
  const size_t wt_f32_off = 6711312ull;                         // after flag (16B aligned)
  const size_t needed_big = (wt_f32_off + WT_ELEMS) * 4;        // ~112.4 MB
  const bool big = ws_size >= needed_big;

  float* ws   = (float*)d_ws;
  float* h    = ws;                                   // 786432
  u16*  yhi   = (u16*)(ws + 786432);                  // planes 2048x384
  u16*  ylo   = yhi + 786432;
  float* qkvb = ws + 1572864;                         // 2359296 f32
  u16*  athi  = (u16*)(ws + 3932160);                 // planes 2048x384
  u16*  atlo  = athi + 786432;
  u16*  ubhi  = (u16*)(ws + 1572864);                 // planes 2048x1536 (alias qkvb+attb)
  u16*  ublo  = ubhi + 3145728;
  float* xn   = ws + 1572864;                         // pre-loop alias
  float* centers;
  int*   keep;
  int*   flag;
  u16 *wthi, *wtlo;
  if(big){
    centers = ws + 6684672;
    keep    = (int*)(ws + 6709248);
    flag    = (int*)(ws + 6711296);
    wthi    = (u16*)(ws + wt_f32_off);
    wtlo    = wthi + WT_ELEMS;
  }else{
    // small path layout: wt planes (pre + 1 layer slot) then tail buffers
    wthi    = (u16*)(ws + 4718592);                   // 1916928 u16 = 958464 f32
    wtlo    = (u16*)(ws + 5677056);                   // 1916928 u16
    centers = ws + 6832128;                           // 24576
    keep    = (int*)(ws + 6856704);                   // 2048
    flag    = (int*)(ws + 6858752);
    if(ws_size < (6858752ull + 16) * 4) return;
  }

  k_normalize<<<NB, 256, 0, stream>>>(pts, xn, flag);
  // fused FPS + keep + weight transposes (512 threads, R9 proven)
  {
    int grid = big ? (64 + 144 + 12*1728) : (64 + 144);
    k_fps_trans<<<grid, 512, 0, stream>>>(xn, centers, noise, keep, pe_w3, pos_w2,
        wqkv, wo, wi, wo2, wthi, wtlo, flag);
  }
  k_knn_embed<<<NB*NLK, 256, 0, stream>>>(xn, centers, keep,
      pe_w1, pe_b1, pe_w2, pe_b2, pos_w1, pos_b1,
      yhi /*mfhi*/, yhi + 2048*256 /*mflo*/, athi /*phhi*/, athi + 2048*128 /*phlo*/, flag);
  k_gemm_mfma<64,0,false,false><<<dim3(6,32), 256, 0, stream>>>(
      yhi, yhi + 2048*256, wthi, wtlo, 0, pe_b3, 0, flag, nullptr, h, nullptr, nullptr, 384, 256);
  k_gemm_mfma<64,0,true ,false><<<dim3(6,32), 256, 0, stream>>>(
      athi, athi + 2048*128, wthi, wtlo, 98304, pos_b2, 0, flag, h, h, nullptr, nullptr, 384, 128);

  for(int l=0; l<NL; l++){
    size_t lb = big ? (PL_PRE + (size_t)l*PL_LAYER) : PL_PRE;
    if(!big){
      k_transpose4<<<1728, 256, 0, stream>>>(wqkv, wo, wi, wo2, l, wthi, wtlo, flag);
    }
    k_ln_split<<<MM, 128, 0, stream>>>(h, ln1, (size_t)l*2*ND, yhi, ylo, flag);
    k_gemm_mfma<64,0,false,false><<<dim3(18,32), 256, 0, stream>>>(
        yhi, ylo, wthi, wtlo, lb, bqkv, (size_t)l*1152, flag, nullptr, qkvb, nullptr, nullptr, 1152, 384);
    k_attn_pl<<<NB*NH, 256, 0, stream>>>(qkvb, athi, atlo);
    k_gemm_mfma<64,0,true ,false><<<dim3(6,32), 256, 0, stream>>>(
        athi, atlo, wthi, wtlo, lb + 442368, bo, (size_t)l*384, flag, h, h, nullptr, nullptr, 384, 384);
    k_ln_split<<<MM, 128, 0, stream>>>(h, ln2, (size_t)l*2*ND, yhi, ylo, flag);
    k_gemm_mfma<64,1,false,true ><<<dim3(24,32), 256, 0, stream>>>(
        yhi, ylo, wthi, wtlo, lb + 589824, bi, (size_t)l*1536, flag, nullptr, nullptr, ubhi, ublo, 1536, 384);
    k_gemm_mfma<64,0,true ,false><<<dim3(6,32), 256, 0, stream>>>(
        ubhi, ublo, wthi, wtlo, lb + 1179648, bo2, (size_t)l*384, flag, h, h, nullptr, nullptr, 384, 1536);
  }
  k_ln<true><<<MM, 128, 0, stream>>>(h, lnf, 0, d_out, flag);
}